// Round 2
// baseline (154.418 us; speedup 1.0000x reference)
//
#include <hip/hip_runtime.h>

#define NQ  4
#define DIM 16
#define NL  3
#define HD  128

__global__ __launch_bounds__(256) void rqa_kernel(
    const float* __restrict__ edge,   // (N,128)
    const float* __restrict__ W,      // (4,128)
    const float* __restrict__ b,      // (4,)
    const float* __restrict__ qw,     // (3,4,3) phi,theta,omega
    float* __restrict__ out, int N)
{
    __shared__ float rotm[NL * NQ][4];   // a_re, a_im, b_re, b_im per Rot gate
    __shared__ float4 accs[256];         // projection result per row of this block

    const int tid = threadIdx.x;
    if (tid < NL * NQ) {
        float phi = qw[tid * 3 + 0];
        float th  = qw[tid * 3 + 1];
        float om  = qw[tid * 3 + 2];
        float ct, st, ca, sa, cb, sb;
        sincosf(0.5f * th, &st, &ct);
        sincosf(0.5f * (phi + om), &sa, &ca);
        sincosf(0.5f * (phi - om), &sb, &cb);
        // U00 = e^{-i(phi+om)/2} c ; U01 = -e^{i(phi-om)/2} s
        rotm[tid][0] =  ca * ct;
        rotm[tid][1] = -sa * ct;
        rotm[tid][2] = -cb * st;
        rotm[tid][3] = -sb * st;
    }

    // ---------- cooperative coalesced projection ----------
    // 4-lane groups: lanes (4g..4g+3) stream row waveBase+p*16+g together.
    const int wid  = tid >> 6;          // wave 0..3
    const int lane = tid & 63;
    const int sub  = lane & 3;          // float4 column phase
    const int rgrp = lane >> 2;         // row-in-group 0..15

    const size_t blockRow0 = (size_t)blockIdx.x * 256;
    const float4* __restrict__ Wv = (const float4*)W;

    #pragma unroll
    for (int p = 0; p < 4; ++p) {
        const int local = wid * 64 + p * 16 + rgrp;
        const size_t r = blockRow0 + local;
        float a0 = 0.f, a1 = 0.f, a2 = 0.f, a3 = 0.f;
        if (r < (size_t)N) {
            const float4* __restrict__ row = (const float4*)(edge + r * HD);
            #pragma unroll
            for (int j = 0; j < 8; ++j) {
                const int c4 = sub + 4 * j;        // 0..31
                float4 x  = row[c4];
                float4 w0 = Wv[0 * 32 + c4];
                float4 w1 = Wv[1 * 32 + c4];
                float4 w2 = Wv[2 * 32 + c4];
                float4 w3 = Wv[3 * 32 + c4];
                a0 += x.x * w0.x + x.y * w0.y + x.z * w0.z + x.w * w0.w;
                a1 += x.x * w1.x + x.y * w1.y + x.z * w1.z + x.w * w1.w;
                a2 += x.x * w2.x + x.y * w2.y + x.z * w2.z + x.w * w2.w;
                a3 += x.x * w3.x + x.y * w3.y + x.z * w3.z + x.w * w3.w;
            }
        }
        a0 += __shfl_xor(a0, 1); a0 += __shfl_xor(a0, 2);
        a1 += __shfl_xor(a1, 1); a1 += __shfl_xor(a1, 2);
        a2 += __shfl_xor(a2, 1); a2 += __shfl_xor(a2, 2);
        a3 += __shfl_xor(a3, 1); a3 += __shfl_xor(a3, 2);
        if (sub == 0)
            accs[local] = make_float4(a0 + b[0], a1 + b[1], a2 + b[2], a3 + b[3]);
    }
    __syncthreads();

    const size_t gid = blockRow0 + tid;
    if (gid >= (size_t)N) return;

    const float4 accv = accs[tid];
    float acc[NQ] = {accv.x, accv.y, accv.z, accv.w};

    // angles (same every layer: data re-uploading) -> cos/sin of a/2
    const float PIF = 3.14159265358979323846f;
    float cy[NQ], sy[NQ];
    #pragma unroll
    for (int w = 0; w < NQ; ++w) {
        float a = PIF * tanhf(acc[w]);
        sincosf(0.5f * a, &sy[w], &cy[w]);
    }

    // ---------- statevector in registers (wire w <-> bit 3-w, wire0 = MSB) ----------
    float sr[DIM], si[DIM];
    #pragma unroll
    for (int n = 0; n < DIM; ++n) { sr[n] = 0.f; si[n] = 0.f; }
    sr[0] = 1.f;

    for (int l = 0; l < NL; ++l) {
        // RY embedding (real rotation) on wires 0..3
        #pragma unroll
        for (int w = 0; w < NQ; ++w) {
            const int str = 1 << (3 - w);
            const float c = cy[w], s = sy[w];
            #pragma unroll
            for (int i0 = 0; i0 < DIM; ++i0) {
                if (i0 & str) continue;
                const int i1 = i0 | str;
                float r0 = c * sr[i0] - s * sr[i1];
                float m0 = c * si[i0] - s * si[i1];
                float r1 = s * sr[i0] + c * sr[i1];
                float m1 = s * si[i0] + c * si[i1];
                sr[i0] = r0; si[i0] = m0; sr[i1] = r1; si[i1] = m1;
            }
        }
        // Rot gates (constant, from LDS broadcast)
        #pragma unroll
        for (int w = 0; w < NQ; ++w) {
            const float ar = rotm[l * NQ + w][0];
            const float ai = rotm[l * NQ + w][1];
            const float br = rotm[l * NQ + w][2];
            const float bi = rotm[l * NQ + w][3];
            const int str = 1 << (3 - w);
            #pragma unroll
            for (int i0 = 0; i0 < DIM; ++i0) {
                if (i0 & str) continue;
                const int i1 = i0 | str;
                const float s0r = sr[i0], s0i = si[i0];
                const float s1r = sr[i1], s1i = si[i1];
                sr[i0] =  ar * s0r - ai * s0i + br * s1r - bi * s1i;
                si[i0] =  ar * s0i + ai * s0r + br * s1i + bi * s1r;
                sr[i1] = -br * s0r - bi * s0i + ar * s1r + ai * s1i;
                si[i1] = -br * s0i + bi * s0r + ar * s1i - ai * s1r;
            }
        }
        // CNOT ring (0,1),(1,2),(2,3),(3,0): register swaps
        #pragma unroll
        for (int w = 0; w < NQ; ++w) {
            const int cb_ = 1 << (3 - w);
            const int tb_ = 1 << (3 - ((w + 1) & 3));
            #pragma unroll
            for (int n = 0; n < DIM; ++n) {
                if ((n & cb_) && !(n & tb_)) {
                    const int m = n | tb_;
                    float t0 = sr[n]; sr[n] = sr[m]; sr[m] = t0;
                    float t1 = si[n]; si[n] = si[m]; si[m] = t1;
                }
            }
        }
    }

    // <Z_0> = sum_{bit3=0} |amp|^2 - sum_{bit3=1} |amp|^2, then sigmoid
    float z = 0.f;
    #pragma unroll
    for (int n = 0; n < DIM; ++n) {
        const float p = sr[n] * sr[n] + si[n] * si[n];
        z = (n < 8) ? (z + p) : (z - p);
    }
    out[gid] = 1.0f / (1.0f + expf(-z));
}

extern "C" void kernel_launch(void* const* d_in, const int* in_sizes, int n_in,
                              void* d_out, int out_size, void* d_ws, size_t ws_size,
                              hipStream_t stream) {
    const float* edge = (const float*)d_in[0];
    const float* W    = (const float*)d_in[1];
    const float* b    = (const float*)d_in[2];
    const float* qw   = (const float*)d_in[3];
    float* out = (float*)d_out;

    const int N = in_sizes[0] / HD;
    const int blocks = (N + 255) / 256;
    rqa_kernel<<<dim3(blocks), dim3(256), 0, stream>>>(edge, W, b, qw, out, N);
}

// Round 3
// 128.300 us; speedup vs baseline: 1.2036x; 1.2036x over previous
//
#include <hip/hip_runtime.h>

#define NQ  4
#define DIM 16
#define NL  3
#define HD  128

__global__ __launch_bounds__(256) void rqa_kernel(
    const float* __restrict__ edge,   // (N,128)
    const float* __restrict__ W,      // (4,128)
    const float* __restrict__ b,      // (4,)
    const float* __restrict__ qw,     // (3,4,3) phi,theta,omega
    float* __restrict__ out, int N)
{
    __shared__ float rotm[NL * NQ][4];   // a_re, a_im, b_re, b_im per Rot gate
    __shared__ float4 part[256][5];      // [row][quad-slot 0..3], [4] = pad (80B stride)

    const int tid = threadIdx.x;
    if (tid < NL * NQ) {
        float phi = qw[tid * 3 + 0];
        float th  = qw[tid * 3 + 1];
        float om  = qw[tid * 3 + 2];
        float ct, st, ca, sa, cb, sb;
        sincosf(0.5f * th, &st, &ct);
        sincosf(0.5f * (phi + om), &sa, &ca);
        sincosf(0.5f * (phi - om), &sb, &cb);
        // U00 = e^{-i(phi+om)/2} c ; U01 = -e^{i(phi-om)/2} s
        rotm[tid][0] =  ca * ct;
        rotm[tid][1] = -sa * ct;
        rotm[tid][2] = -cb * st;
        rotm[tid][3] = -sb * st;
    }

    // ---------- cooperative projection: 16-lane group per row ----------
    const int lane = tid & 63;
    const int wid  = tid >> 6;     // wave 0..3
    const int sub  = lane & 15;    // granule phase within row
    const int grp  = lane >> 4;    // row-in-pass 0..3

    // W fragment for this lane, loaded ONCE (granules sub and sub+16 of each output row)
    const float4* __restrict__ Wv = (const float4*)W;
    const float4 w00 = Wv[0 * 32 + sub], w01 = Wv[0 * 32 + sub + 16];
    const float4 w10 = Wv[1 * 32 + sub], w11 = Wv[1 * 32 + sub + 16];
    const float4 w20 = Wv[2 * 32 + sub], w21 = Wv[2 * 32 + sub + 16];
    const float4 w30 = Wv[3 * 32 + sub], w31 = Wv[3 * 32 + sub + 16];

    const size_t blockRow0 = (size_t)blockIdx.x * 256;

    #pragma unroll 4
    for (int p = 0; p < 16; ++p) {
        const int local = wid * 64 + p * 4 + grp;
        const size_t r = blockRow0 + local;
        if (r < (size_t)N) {
            const float4* __restrict__ row = (const float4*)(edge + r * HD);
            const float4 x0 = row[sub];
            const float4 x1 = row[sub + 16];
            float a0 = x0.x*w00.x + x0.y*w00.y + x0.z*w00.z + x0.w*w00.w
                     + x1.x*w01.x + x1.y*w01.y + x1.z*w01.z + x1.w*w01.w;
            float a1 = x0.x*w10.x + x0.y*w10.y + x0.z*w10.z + x0.w*w10.w
                     + x1.x*w11.x + x1.y*w11.y + x1.z*w11.z + x1.w*w11.w;
            float a2 = x0.x*w20.x + x0.y*w20.y + x0.z*w20.z + x0.w*w20.w
                     + x1.x*w21.x + x1.y*w21.y + x1.z*w21.z + x1.w*w21.w;
            float a3 = x0.x*w30.x + x0.y*w30.y + x0.z*w30.z + x0.w*w30.w
                     + x1.x*w31.x + x1.y*w31.y + x1.z*w31.z + x1.w*w31.w;
            // quad reduction (lanes sub, sub^1, sub^2, sub^3)
            a0 += __shfl_xor(a0, 1); a0 += __shfl_xor(a0, 2);
            a1 += __shfl_xor(a1, 1); a1 += __shfl_xor(a1, 2);
            a2 += __shfl_xor(a2, 1); a2 += __shfl_xor(a2, 2);
            a3 += __shfl_xor(a3, 1); a3 += __shfl_xor(a3, 2);
            if ((sub & 3) == 0)
                part[local][sub >> 2] = make_float4(a0, a1, a2, a3);
        }
    }
    __syncthreads();

    const size_t gid = blockRow0 + tid;
    if (gid >= (size_t)N) return;

    const float4 p0 = part[tid][0];
    const float4 p1 = part[tid][1];
    const float4 p2 = part[tid][2];
    const float4 p3 = part[tid][3];
    float acc[NQ] = { p0.x + p1.x + p2.x + p3.x + b[0],
                      p0.y + p1.y + p2.y + p3.y + b[1],
                      p0.z + p1.z + p2.z + p3.z + b[2],
                      p0.w + p1.w + p2.w + p3.w + b[3] };

    // angles (same every layer: data re-uploading) -> cos/sin of a/2
    const float PIF = 3.14159265358979323846f;
    float cy[NQ], sy[NQ];
    #pragma unroll
    for (int w = 0; w < NQ; ++w) {
        float a = PIF * tanhf(acc[w]);
        sincosf(0.5f * a, &sy[w], &cy[w]);
    }

    // ---------- statevector in registers (wire w <-> bit 3-w, wire0 = MSB) ----------
    float sr[DIM], si[DIM];
    #pragma unroll
    for (int n = 0; n < DIM; ++n) { sr[n] = 0.f; si[n] = 0.f; }
    sr[0] = 1.f;

    for (int l = 0; l < NL; ++l) {
        // RY embedding (real rotation) on wires 0..3
        #pragma unroll
        for (int w = 0; w < NQ; ++w) {
            const int str = 1 << (3 - w);
            const float c = cy[w], s = sy[w];
            #pragma unroll
            for (int i0 = 0; i0 < DIM; ++i0) {
                if (i0 & str) continue;
                const int i1 = i0 | str;
                float r0 = c * sr[i0] - s * sr[i1];
                float m0 = c * si[i0] - s * si[i1];
                float r1 = s * sr[i0] + c * sr[i1];
                float m1 = s * si[i0] + c * si[i1];
                sr[i0] = r0; si[i0] = m0; sr[i1] = r1; si[i1] = m1;
            }
        }
        // Rot gates (constant, from LDS broadcast)
        #pragma unroll
        for (int w = 0; w < NQ; ++w) {
            const float ar = rotm[l * NQ + w][0];
            const float ai = rotm[l * NQ + w][1];
            const float br = rotm[l * NQ + w][2];
            const float bi = rotm[l * NQ + w][3];
            const int str = 1 << (3 - w);
            #pragma unroll
            for (int i0 = 0; i0 < DIM; ++i0) {
                if (i0 & str) continue;
                const int i1 = i0 | str;
                const float s0r = sr[i0], s0i = si[i0];
                const float s1r = sr[i1], s1i = si[i1];
                sr[i0] =  ar * s0r - ai * s0i + br * s1r - bi * s1i;
                si[i0] =  ar * s0i + ai * s0r + br * s1i + bi * s1r;
                sr[i1] = -br * s0r - bi * s0i + ar * s1r + ai * s1i;
                si[i1] = -br * s0i + bi * s0r + ar * s1i - ai * s1r;
            }
        }
        // CNOT ring (0,1),(1,2),(2,3),(3,0): register swaps
        #pragma unroll
        for (int w = 0; w < NQ; ++w) {
            const int cb_ = 1 << (3 - w);
            const int tb_ = 1 << (3 - ((w + 1) & 3));
            #pragma unroll
            for (int n = 0; n < DIM; ++n) {
                if ((n & cb_) && !(n & tb_)) {
                    const int m = n | tb_;
                    float t0 = sr[n]; sr[n] = sr[m]; sr[m] = t0;
                    float t1 = si[n]; si[n] = si[m]; si[m] = t1;
                }
            }
        }
    }

    // <Z_0> = sum_{bit3=0} |amp|^2 - sum_{bit3=1} |amp|^2, then sigmoid
    float z = 0.f;
    #pragma unroll
    for (int n = 0; n < DIM; ++n) {
        const float p = sr[n] * sr[n] + si[n] * si[n];
        z = (n < 8) ? (z + p) : (z - p);
    }
    out[gid] = 1.0f / (1.0f + expf(-z));
}

extern "C" void kernel_launch(void* const* d_in, const int* in_sizes, int n_in,
                              void* d_out, int out_size, void* d_ws, size_t ws_size,
                              hipStream_t stream) {
    const float* edge = (const float*)d_in[0];
    const float* W    = (const float*)d_in[1];
    const float* b    = (const float*)d_in[2];
    const float* qw   = (const float*)d_in[3];
    float* out = (float*)d_out;

    const int N = in_sizes[0] / HD;
    const int blocks = (N + 255) / 256;
    rqa_kernel<<<dim3(blocks), dim3(256), 0, stream>>>(edge, W, b, qw, out, N);
}